// Round 3
// baseline (8492.783 us; speedup 1.0000x reference)
//
#include <hip/hip_runtime.h>
#include <hip/hip_bf16.h>

#define B_ 64
#define S_ 256
#define IN_ 512
#define H_ 1024
#define O_ 512
#define K_ 4
#define T_ (S_*K_)      // 1024
#define H3_ (3*H_)      // 3072

#define NC_ 4           // clusters
#define CPC_ 64         // WGs (CUs) per cluster
#define RPC_ 16         // batch rows per cluster

typedef __attribute__((ext_vector_type(8))) short bf16x8;
typedef __attribute__((ext_vector_type(4))) float f32x4;
typedef unsigned short ushort_t;
typedef unsigned int uint_t;
typedef unsigned long long ull_t;

__device__ __forceinline__ ushort_t f2b(float f) {
    union { float f; unsigned u; } v; v.f = f;
    unsigned r = v.u + 0x7FFFu + ((v.u >> 16) & 1u);
    return (ushort_t)(r >> 16);
}
__device__ __forceinline__ float b2f(ushort_t h) {
    union { unsigned u; float f; } v; v.u = ((unsigned)h) << 16; return v.f;
}

// ---------------------------------------------------------------------------
// gi = x @ W_ih^T + b_ih   (bf16 output), M=16384, N=3072, K=512
// ---------------------------------------------------------------------------
__global__ __launch_bounds__(256) void gi_gemm(const float* __restrict__ x,
                                               const float* __restrict__ Wih,
                                               const float* __restrict__ bih,
                                               ushort_t* __restrict__ gi) {
    const int NB = H3_ / 64;                 // 48
    const int nb = blockIdx.x % NB;
    const int mb = blockIdx.x / NB;
    const int tid = threadIdx.x, lane = tid & 63, w = tid >> 6;
    const int wm = w >> 1, wn = w & 1;
    __shared__ ushort_t Al[64][40];
    __shared__ ushort_t Bl[64][40];
    f32x4 acc[2][2] = {};
    const int lrow = tid >> 2, lk = (tid & 3) * 8;
    for (int k0 = 0; k0 < IN_; k0 += 32) {
        const float* xs = &x[(size_t)(mb*64 + lrow)*IN_ + k0 + lk];
        const float* ws = &Wih[(size_t)(nb*64 + lrow)*IN_ + k0 + lk];
        #pragma unroll
        for (int i = 0; i < 8; ++i) Al[lrow][lk+i] = f2b(xs[i]);
        #pragma unroll
        for (int i = 0; i < 8; ++i) Bl[lrow][lk+i] = f2b(ws[i]);
        __syncthreads();
        const int fr = lane & 15, fk = (lane >> 4) * 8;
        #pragma unroll
        for (int mt = 0; mt < 2; ++mt) {
            bf16x8 a = *(const bf16x8*)&Al[wm*32 + mt*16 + fr][fk];
            #pragma unroll
            for (int nt = 0; nt < 2; ++nt) {
                bf16x8 b = *(const bf16x8*)&Bl[wn*32 + nt*16 + fr][fk];
                acc[mt][nt] = __builtin_amdgcn_mfma_f32_16x16x32_bf16(a, b, acc[mt][nt], 0, 0, 0);
            }
        }
        __syncthreads();
    }
    const int fr = lane & 15, fm = (lane >> 4) * 4;
    #pragma unroll
    for (int mt = 0; mt < 2; ++mt)
    #pragma unroll
    for (int nt = 0; nt < 2; ++nt)
    #pragma unroll
    for (int i = 0; i < 4; ++i) {
        int gm = mb*64 + wm*32 + mt*16 + fm + i;
        int gn = nb*64 + wn*32 + nt*16 + fr;
        gi[(size_t)gm*H3_ + gn] = f2b(acc[mt][nt][i] + bih[gn]);
    }
}

// ---------------------------------------------------------------------------
// Persistent recurrent kernel. 256 WGs = 4 clusters x 64 WGs. One WG per CU.
// h-exchange via dedicated 256KB ping-pong xbuf (MALL-hot, bypass atomics);
// hstates trajectory via plain cached stores (read by logits_gemm later).
// Per-tick sync: per-WG monotonic flag, wave-0 polls 64 flags RELAXED.
// ---------------------------------------------------------------------------
__global__ __launch_bounds__(256) void rec_kernel(const ushort_t* __restrict__ gi,
                                                  const float* __restrict__ Whh,
                                                  const float* __restrict__ bhh,
                                                  ushort_t* __restrict__ hstates,
                                                  ushort_t* __restrict__ xbuf,
                                                  int* __restrict__ flags) {
    const int wg = blockIdx.x;
    const int c  = wg >> 6;        // cluster
    const int cu = wg & 63;        // position within cluster
    const int tid = threadIdx.x, lane = tid & 63, w = tid >> 6;
    const int r_el = tid >> 4, jl = tid & 15;   // elementwise mapping
    const int colbase = cu << 4;                // 16 h-cols per WG
    const int b0 = c * RPC_;                    // batch row base

    __shared__ ushort_t wlds[3][16][1032];      // 99072 B   W_hh slice (bf16)
    __shared__ ushort_t hlds[16][1032];         // 33024 B   cluster h (bf16)
    __shared__ float red[4][16][49];            // 12544 B   per-wave partials

    // Load W_hh slice once: gate g, local col j -> row g*1024 + colbase + j
    for (int idx = tid; idx < 3*16*1024; idx += 256) {
        int g = idx >> 14, rem = idx & 16383;
        int j = rem >> 10, k = rem & 1023;
        wlds[g][j][k] = f2b(Whh[(size_t)(g*H_ + colbase + j)*H_ + k]);
    }
    const float bh_r = bhh[colbase + jl];
    const float bh_z = bhh[H_ + colbase + jl];
    const float bh_n = bhh[2*H_ + colbase + jl];

    // zero h tile (t=0 reads zeros)
    for (int idx = tid; idx < 16*516; idx += 256) ((uint_t*)hlds)[idx] = 0u;

    // gi double-buffer: current (g_*) loaded now, next (p_*) prefetched in
    // phase C at each s-boundary.
    ushort_t g_r, g_z, g_n, p_r = 0, p_z = 0, p_n = 0;
    {
        size_t row = ((size_t)(b0 + r_el)*S_ + 0)*H3_ + colbase + jl;
        g_r = gi[row]; g_z = gi[row + H_]; g_n = gi[row + 2*H_];
    }
    float gir = 0.f, giz = 0.f, gin = 0.f;

    float h_prev = 0.f;
    int* cflags = &flags[c << 6];   // 64 ints per cluster

    for (int t = 0; t < T_; ++t) {
        if ((t & 3) == 0) {
            if (t > 0) { g_r = p_r; g_z = p_z; g_n = p_n; }
            gir = b2f(g_r); giz = b2f(g_z); gin = b2f(g_n);
        }
        // stage cluster h(t-1) from xbuf slot (t-1)&1 (bypass, MALL-hot)
        if (t > 0) {
            const ull_t* xsrc = (const ull_t*)xbuf;   // 256 ull per row
            #pragma unroll
            for (int idx = tid; idx < 16*256; idx += 256) {
                int rr = idx >> 8, kq = idx & 255;
                ull_t v = __hip_atomic_load(
                    &xsrc[(((size_t)((t-1) & 1)*64) + b0 + rr)*256 + kq],
                    __ATOMIC_RELAXED, __HIP_MEMORY_SCOPE_AGENT);
                *(ull_t*)&hlds[rr][kq << 2] = v;
            }
        }
        __syncthreads();

        // MFMA: wave w covers k in [w*256, w*256+256); 3 gates, M=16 tile
        f32x4 acc0 = {}, acc1 = {}, acc2 = {};
        {
            const int fr = lane & 15, koff = (lane >> 4) << 3;
            #pragma unroll
            for (int ks = 0; ks < 8; ++ks) {
                int k = (w << 8) + (ks << 5) + koff;
                bf16x8 a  = *(const bf16x8*)&hlds[fr][k];
                bf16x8 b0v = *(const bf16x8*)&wlds[0][fr][k];
                bf16x8 b1v = *(const bf16x8*)&wlds[1][fr][k];
                bf16x8 b2v = *(const bf16x8*)&wlds[2][fr][k];
                acc0 = __builtin_amdgcn_mfma_f32_16x16x32_bf16(a, b0v, acc0, 0, 0, 0);
                acc1 = __builtin_amdgcn_mfma_f32_16x16x32_bf16(a, b1v, acc1, 0, 0, 0);
                acc2 = __builtin_amdgcn_mfma_f32_16x16x32_bf16(a, b2v, acc2, 0, 0, 0);
            }
        }
        {
            const int n = lane & 15, m = (lane >> 4) << 2;
            #pragma unroll
            for (int i = 0; i < 4; ++i) {
                red[w][m+i][n]      = acc0[i];
                red[w][m+i][16+n]   = acc1[i];
                red[w][m+i][32+n]   = acc2[i];
            }
        }
        __syncthreads();

        // elementwise GRU update: thread (r_el, jl)
        float ghr = red[0][r_el][jl]    + red[1][r_el][jl]    + red[2][r_el][jl]    + red[3][r_el][jl];
        float ghz = red[0][r_el][16+jl] + red[1][r_el][16+jl] + red[2][r_el][16+jl] + red[3][r_el][16+jl];
        float ghn = red[0][r_el][32+jl] + red[1][r_el][32+jl] + red[2][r_el][32+jl] + red[3][r_el][32+jl];
        float rr_ = 1.f / (1.f + __expf(-(gir + ghr + bh_r)));
        float zz  = 1.f / (1.f + __expf(-(giz + ghz + bh_z)));
        float nn  = tanhf(gin + rr_ * (ghn + bh_n));
        float hn  = (1.f - zz) * nn + zz * h_prev;
        h_prev = hn;
        ushort_t hb = f2b(hn);

        // trajectory: plain cached store (L2-ack, read by logits_gemm later)
        hstates[((size_t)(b0 + r_el)*T_ + t)*H_ + colbase + jl] = hb;
        // exchange: bypass store into ping-pong slot t&1
        __hip_atomic_store(&xbuf[(((size_t)(t & 1)*64) + b0 + r_el)*H_ + colbase + jl],
                           hb, __ATOMIC_RELAXED, __HIP_MEMORY_SCOPE_AGENT);

        // prefetch next timestep's gi rows (latency merges with store-ack wait)
        if ((t & 3) == 0) {
            int sn = (t >> 2) + 1; if (sn > S_ - 1) sn = S_ - 1;
            size_t row = ((size_t)(b0 + r_el)*S_ + sn)*H3_ + colbase + jl;
            p_r = gi[row]; p_z = gi[row + H_]; p_n = gi[row + 2*H_];
        }

        // barrier drains vmcnt(0) in every wave -> all stores acked (xbuf at
        // MALL) before the flag is raised.
        __syncthreads();

        if (w == 0) {
            if (lane == 0)
                __hip_atomic_store(&cflags[cu], t + 1, __ATOMIC_RELAXED,
                                   __HIP_MEMORY_SCOPE_AGENT);
            for (;;) {
                int v = __hip_atomic_load(&cflags[lane], __ATOMIC_RELAXED,
                                          __HIP_MEMORY_SCOPE_AGENT);
                if (__all(v >= t + 1)) break;
                __builtin_amdgcn_s_sleep(1);
            }
        }
        __syncthreads();
    }
}

// ---------------------------------------------------------------------------
// logits = (hstates @ W_fc^T + b_fc) * seq_mask  (f32 out, straight to d_out)
// M = 65536 (b*T + t), N = 512, K = 1024
// ---------------------------------------------------------------------------
__global__ __launch_bounds__(256) void logits_gemm(const ushort_t* __restrict__ hstates,
                                                   const float* __restrict__ Wfc,
                                                   const float* __restrict__ bfc,
                                                   const float* __restrict__ sm,
                                                   float* __restrict__ out) {
    const int NB = O_ / 64;                  // 8
    const int nb = blockIdx.x % NB;
    const int mb = blockIdx.x / NB;
    const int tid = threadIdx.x, lane = tid & 63, w = tid >> 6;
    const int wm = w >> 1, wn = w & 1;
    __shared__ ushort_t Al[64][40];
    __shared__ ushort_t Bl[64][40];
    f32x4 acc[2][2] = {};
    const int lrow = tid >> 2, lk = (tid & 3) * 8;
    for (int k0 = 0; k0 < H_; k0 += 32) {
        uint4 va = *(const uint4*)&hstates[(size_t)(mb*64 + lrow)*H_ + k0 + lk];
        *(uint4*)&Al[lrow][lk] = va;
        const float* ws = &Wfc[(size_t)(nb*64 + lrow)*H_ + k0 + lk];
        #pragma unroll
        for (int i = 0; i < 8; ++i) Bl[lrow][lk+i] = f2b(ws[i]);
        __syncthreads();
        const int fr = lane & 15, fk = (lane >> 4) * 8;
        #pragma unroll
        for (int mt = 0; mt < 2; ++mt) {
            bf16x8 a = *(const bf16x8*)&Al[wm*32 + mt*16 + fr][fk];
            #pragma unroll
            for (int nt = 0; nt < 2; ++nt) {
                bf16x8 b = *(const bf16x8*)&Bl[wn*32 + nt*16 + fr][fk];
                acc[mt][nt] = __builtin_amdgcn_mfma_f32_16x16x32_bf16(a, b, acc[mt][nt], 0, 0, 0);
            }
        }
        __syncthreads();
    }
    const int fr = lane & 15, fm = (lane >> 4) * 4;
    #pragma unroll
    for (int mt = 0; mt < 2; ++mt)
    #pragma unroll
    for (int nt = 0; nt < 2; ++nt)
    #pragma unroll
    for (int i = 0; i < 4; ++i) {
        int R  = mb*64 + wm*32 + mt*16 + fm + i;     // b*T + t
        int gn = nb*64 + wn*32 + nt*16 + fr;
        int b  = R >> 10, t = R & (T_ - 1);
        float mval = sm[b*S_ + (t >> 2)];
        out[(size_t)R*O_ + gn] = (acc[mt][nt][i] + bfc[gn]) * mval;
    }
}

// ---------------------------------------------------------------------------
// y_res (as f32) and ok (as f32 0/1)
// ---------------------------------------------------------------------------
__global__ void tail_kernel(const int* __restrict__ y, const float* __restrict__ sm,
                            float* __restrict__ yout, float* __restrict__ okout) {
    int i = blockIdx.x * 256 + threadIdx.x;
    if (i < B_ * T_) {
        int b = i >> 10, t = i & 1023, s = t >> 2;
        yout[i]  = (float)y[b*S_ + s];
        okout[i] = (sm[b*S_ + s] != 0.0f) ? 1.0f : 0.0f;
    }
}

// ---------------------------------------------------------------------------
extern "C" void kernel_launch(void* const* d_in, const int* in_sizes, int n_in,
                              void* d_out, int out_size, void* d_ws, size_t ws_size,
                              hipStream_t stream) {
    (void)in_sizes; (void)n_in; (void)out_size; (void)ws_size;
    const float* x   = (const float*)d_in[0];
    const int*   y   = (const int*)d_in[1];
    const float* sm  = (const float*)d_in[2];
    const float* Wih = (const float*)d_in[4];
    const float* Whh = (const float*)d_in[5];
    const float* bih = (const float*)d_in[6];
    const float* bhh = (const float*)d_in[7];
    const float* Wfc = (const float*)d_in[8];
    const float* bfc = (const float*)d_in[9];

    char* ws = (char*)d_ws;
    ushort_t* gi      = (ushort_t*)ws;                                  // 100,663,296 B
    ushort_t* hstates = (ushort_t*)(ws + 100663296);                    // 134,217,728 B
    ushort_t* xbuf    = (ushort_t*)(ws + 100663296 + 134217728);        //     262,144 B
    int*      flags   = (int*)(ws + 100663296 + 134217728 + 262144);    //       4 KB

    hipMemsetAsync(flags, 0, 4096, stream);

    hipLaunchKernelGGL(gi_gemm, dim3((B_*S_/64)*(H3_/64)), dim3(256), 0, stream,
                       x, Wih, bih, gi);

    void* args[] = { (void*)&gi, (void*)&Whh, (void*)&bhh, (void*)&hstates,
                     (void*)&xbuf, (void*)&flags };
    hipLaunchCooperativeKernel((void*)rec_kernel, dim3(NC_*CPC_), dim3(256), args, 0, stream);

    hipLaunchKernelGGL(logits_gemm, dim3((B_*T_/64)*(O_/64)), dim3(256), 0, stream,
                       hstates, Wfc, bfc, sm, (float*)d_out);

    float* yout  = (float*)d_out + (size_t)B_*T_*O_;
    float* okout = yout + (size_t)B_*T_;
    hipLaunchKernelGGL(tail_kernel, dim3(B_*T_/256), dim3(256), 0, stream,
                       y, sm, yout, okout);
}

// Round 5
// 5867.369 us; speedup vs baseline: 1.4475x; 1.4475x over previous
//
#include <hip/hip_runtime.h>
#include <hip/hip_bf16.h>

#define B_ 64
#define S_ 256
#define IN_ 512
#define H_ 1024
#define O_ 512
#define K_ 4
#define T_ (S_*K_)      // 1024
#define H3_ (3*H_)      // 3072

#define NC_ 4           // clusters
#define CPC_ 64         // WGs (CUs) per cluster
#define RPC_ 16         // batch rows per cluster

typedef __attribute__((ext_vector_type(8))) short bf16x8;
typedef __attribute__((ext_vector_type(4))) float f32x4;
typedef __attribute__((ext_vector_type(4))) unsigned int uint32x4;
typedef unsigned short ushort_t;
typedef unsigned int uint_t;
typedef unsigned long long ull_t;

__device__ __forceinline__ ushort_t f2b(float f) {
    union { float f; unsigned u; } v; v.f = f;
    unsigned r = v.u + 0x7FFFu + ((v.u >> 16) & 1u);
    return (ushort_t)(r >> 16);
}
__device__ __forceinline__ float b2f(ushort_t h) {
    union { unsigned u; float f; } v; v.u = ((unsigned)h) << 16; return v.f;
}

// ---------------------------------------------------------------------------
// gi = x @ W_ih^T + b_ih   (bf16 output), M=16384, N=3072, K=512
// ---------------------------------------------------------------------------
__global__ __launch_bounds__(256) void gi_gemm(const float* __restrict__ x,
                                               const float* __restrict__ Wih,
                                               const float* __restrict__ bih,
                                               ushort_t* __restrict__ gi) {
    const int NB = H3_ / 64;                 // 48
    const int nb = blockIdx.x % NB;
    const int mb = blockIdx.x / NB;
    const int tid = threadIdx.x, lane = tid & 63, w = tid >> 6;
    const int wm = w >> 1, wn = w & 1;
    __shared__ ushort_t Al[64][40];
    __shared__ ushort_t Bl[64][40];
    f32x4 acc[2][2] = {};
    const int lrow = tid >> 2, lk = (tid & 3) * 8;
    for (int k0 = 0; k0 < IN_; k0 += 32) {
        const float* xs = &x[(size_t)(mb*64 + lrow)*IN_ + k0 + lk];
        const float* ws = &Wih[(size_t)(nb*64 + lrow)*IN_ + k0 + lk];
        #pragma unroll
        for (int i = 0; i < 8; ++i) Al[lrow][lk+i] = f2b(xs[i]);
        #pragma unroll
        for (int i = 0; i < 8; ++i) Bl[lrow][lk+i] = f2b(ws[i]);
        __syncthreads();
        const int fr = lane & 15, fk = (lane >> 4) * 8;
        #pragma unroll
        for (int mt = 0; mt < 2; ++mt) {
            bf16x8 a = *(const bf16x8*)&Al[wm*32 + mt*16 + fr][fk];
            #pragma unroll
            for (int nt = 0; nt < 2; ++nt) {
                bf16x8 b = *(const bf16x8*)&Bl[wn*32 + nt*16 + fr][fk];
                acc[mt][nt] = __builtin_amdgcn_mfma_f32_16x16x32_bf16(a, b, acc[mt][nt], 0, 0, 0);
            }
        }
        __syncthreads();
    }
    const int fr = lane & 15, fm = (lane >> 4) * 4;
    #pragma unroll
    for (int mt = 0; mt < 2; ++mt)
    #pragma unroll
    for (int nt = 0; nt < 2; ++nt)
    #pragma unroll
    for (int i = 0; i < 4; ++i) {
        int gm = mb*64 + wm*32 + mt*16 + fm + i;
        int gn = nb*64 + wn*32 + nt*16 + fr;
        gi[(size_t)gm*H3_ + gn] = f2b(acc[mt][nt][i] + bih[gn]);
    }
}

// ---------------------------------------------------------------------------
// Persistent recurrent kernel. 256 WGs = 4 clusters x 64 WGs. One WG per CU.
// Per tick each wave loads its own MFMA A-fragments straight from the xbuf
// ping-pong slot with ONE pipelined asm block of 8 bypass (sc0 sc1) dwordx4
// loads + a single vmcnt(0). Outputs are EARLY-CLOBBER so the allocator
// cannot overlap them with the address pair (the R4 NaN bug).
// ---------------------------------------------------------------------------
__global__ __launch_bounds__(256) void rec_kernel(const ushort_t* __restrict__ gi,
                                                  const float* __restrict__ Whh,
                                                  const float* __restrict__ bhh,
                                                  ushort_t* __restrict__ hstates,
                                                  ushort_t* __restrict__ xbuf,
                                                  int* __restrict__ flags) {
    const int wg = blockIdx.x;
    const int c  = wg >> 6;        // cluster
    const int cu = wg & 63;        // position within cluster
    const int tid = threadIdx.x, lane = tid & 63, w = tid >> 6;
    const int r_el = tid >> 4, jl = tid & 15;   // elementwise mapping
    const int colbase = cu << 4;                // 16 h-cols per WG
    const int b0 = c * RPC_;                    // batch row base

    __shared__ ushort_t wlds[3][16][1032];      // 99072 B   W_hh slice (bf16)
    __shared__ float red[4][16][50];            // 12800 B   per-wave partials

    // Load W_hh slice once: gate g, local col j -> row g*1024 + colbase + j
    for (int idx = tid; idx < 3*16*1024; idx += 256) {
        int g = idx >> 14, rem = idx & 16383;
        int j = rem >> 10, k = rem & 1023;
        wlds[g][j][k] = f2b(Whh[(size_t)(g*H_ + colbase + j)*H_ + k]);
    }
    const float bh_r = bhh[colbase + jl];
    const float bh_z = bhh[H_ + colbase + jl];
    const float bh_n = bhh[2*H_ + colbase + jl];

    // gi double-buffer: current (g_*), next (p_*) prefetched at tick top.
    ushort_t g_r, g_z, g_n, p_r = 0, p_z = 0, p_n = 0;
    {
        size_t row = ((size_t)(b0 + r_el)*S_ + 0)*H3_ + colbase + jl;
        g_r = gi[row]; g_z = gi[row + H_]; g_n = gi[row + 2*H_];
    }
    float gir = 0.f, giz = 0.f, gin = 0.f;

    // per-lane constant part of the A-fragment address
    const int fr = lane & 15, koff8 = (lane >> 4) << 3;   // MFMA A layout
    const char* xb_lane = (const char*)xbuf
        + (size_t)(b0 + fr) * (H_ * 2)      // batch row
        + (w << 9)                          // wave's K-quarter (256 els)
        + ((lane >> 4) << 4);               // 16B sub-chunk

    float h_prev = 0.f;
    int* cflags = &flags[c << 6];   // 64 ints per cluster

    for (int t = 0; t < T_; ++t) {
        // ---- tick top: gi consume + prefetch (latency hidden by whole tick)
        if ((t & 3) == 0) {
            if (t > 0) { g_r = p_r; g_z = p_z; g_n = p_n; }
            gir = b2f(g_r); giz = b2f(g_z); gin = b2f(g_n);
            int sn = (t >> 2) + 1; if (sn > S_ - 1) sn = S_ - 1;
            size_t row = ((size_t)(b0 + r_el)*S_ + sn)*H3_ + colbase + jl;
            p_r = gi[row]; p_z = gi[row + H_]; p_n = gi[row + 2*H_];
        }

        // ---- A-fragments: 8 pipelined bypass loads + one vmcnt(0)
        uint32x4 f0 = {}, f1 = {}, f2 = {}, f3 = {}, f4 = {}, f5 = {}, f6 = {}, f7 = {};
        if (t > 0) {
            const char* ab = xb_lane + (((size_t)((t - 1) & 1)) << 17);
            asm volatile(
                "global_load_dwordx4 %0, %8, off sc0 sc1\n\t"
                "global_load_dwordx4 %1, %8, off offset:64 sc0 sc1\n\t"
                "global_load_dwordx4 %2, %8, off offset:128 sc0 sc1\n\t"
                "global_load_dwordx4 %3, %8, off offset:192 sc0 sc1\n\t"
                "global_load_dwordx4 %4, %8, off offset:256 sc0 sc1\n\t"
                "global_load_dwordx4 %5, %8, off offset:320 sc0 sc1\n\t"
                "global_load_dwordx4 %6, %8, off offset:384 sc0 sc1\n\t"
                "global_load_dwordx4 %7, %8, off offset:448 sc0 sc1\n\t"
                "s_waitcnt vmcnt(0)"
                : "=&v"(f0), "=&v"(f1), "=&v"(f2), "=&v"(f3),
                  "=&v"(f4), "=&v"(f5), "=&v"(f6), "=&v"(f7)
                : "v"(ab)
                : "memory");
            __builtin_amdgcn_sched_barrier(0);
        }
        bf16x8 afr[8];
        afr[0] = *(bf16x8*)&f0; afr[1] = *(bf16x8*)&f1;
        afr[2] = *(bf16x8*)&f2; afr[3] = *(bf16x8*)&f3;
        afr[4] = *(bf16x8*)&f4; afr[5] = *(bf16x8*)&f5;
        afr[6] = *(bf16x8*)&f6; afr[7] = *(bf16x8*)&f7;

        // ---- MFMA: wave w covers k in [w*256, w*256+256); 3 gates
        f32x4 acc0 = {}, acc1 = {}, acc2 = {};
        #pragma unroll
        for (int ks = 0; ks < 8; ++ks) {
            int k = (w << 8) + (ks << 5) + koff8;
            bf16x8 b0v = *(const bf16x8*)&wlds[0][fr][k];
            bf16x8 b1v = *(const bf16x8*)&wlds[1][fr][k];
            bf16x8 b2v = *(const bf16x8*)&wlds[2][fr][k];
            acc0 = __builtin_amdgcn_mfma_f32_16x16x32_bf16(afr[ks], b0v, acc0, 0, 0, 0);
            acc1 = __builtin_amdgcn_mfma_f32_16x16x32_bf16(afr[ks], b1v, acc1, 0, 0, 0);
            acc2 = __builtin_amdgcn_mfma_f32_16x16x32_bf16(afr[ks], b2v, acc2, 0, 0, 0);
        }
        {
            const int n = lane & 15, m = (lane >> 4) << 2;
            #pragma unroll
            for (int i = 0; i < 4; ++i) {
                red[w][m+i][n]      = acc0[i];
                red[w][m+i][16+n]   = acc1[i];
                red[w][m+i][32+n]   = acc2[i];
            }
        }
        __syncthreads();

        // ---- elementwise GRU update: thread (r_el, jl)
        float ghr = red[0][r_el][jl]    + red[1][r_el][jl]    + red[2][r_el][jl]    + red[3][r_el][jl];
        float ghz = red[0][r_el][16+jl] + red[1][r_el][16+jl] + red[2][r_el][16+jl] + red[3][r_el][16+jl];
        float ghn = red[0][r_el][32+jl] + red[1][r_el][32+jl] + red[2][r_el][32+jl] + red[3][r_el][32+jl];
        float rr_ = 1.f / (1.f + __expf(-(gir + ghr + bh_r)));
        float zz  = 1.f / (1.f + __expf(-(giz + ghz + bh_z)));
        float nn  = tanhf(gin + rr_ * (ghn + bh_n));
        float hn  = (1.f - zz) * nn + zz * h_prev;
        h_prev = hn;
        ushort_t hb = f2b(hn);

        // trajectory: plain cached store (read by logits_gemm later)
        hstates[((size_t)(b0 + r_el)*T_ + t)*H_ + colbase + jl] = hb;
        // exchange: bypass store into ping-pong slot t&1
        __hip_atomic_store(&xbuf[(((size_t)(t & 1)*64) + b0 + r_el)*H_ + colbase + jl],
                           hb, __ATOMIC_RELAXED, __HIP_MEMORY_SCOPE_AGENT);

        // barrier drains vmcnt(0) in every wave -> stores acked at MALL
        __syncthreads();

        if (w == 0) {
            if (lane == 0)
                __hip_atomic_store(&cflags[cu], t + 1, __ATOMIC_RELAXED,
                                   __HIP_MEMORY_SCOPE_AGENT);
            for (;;) {
                int v = __hip_atomic_load(&cflags[lane], __ATOMIC_RELAXED,
                                          __HIP_MEMORY_SCOPE_AGENT);
                if (__all(v >= t + 1)) break;
                __builtin_amdgcn_s_sleep(1);
            }
        }
        __syncthreads();
    }
}

// ---------------------------------------------------------------------------
// logits = (hstates @ W_fc^T + b_fc) * seq_mask  (f32 out, straight to d_out)
// M = 65536 (b*T + t), N = 512, K = 1024
// ---------------------------------------------------------------------------
__global__ __launch_bounds__(256) void logits_gemm(const ushort_t* __restrict__ hstates,
                                                   const float* __restrict__ Wfc,
                                                   const float* __restrict__ bfc,
                                                   const float* __restrict__ sm,
                                                   float* __restrict__ out) {
    const int NB = O_ / 64;                  // 8
    const int nb = blockIdx.x % NB;
    const int mb = blockIdx.x / NB;
    const int tid = threadIdx.x, lane = tid & 63, w = tid >> 6;
    const int wm = w >> 1, wn = w & 1;
    __shared__ ushort_t Al[64][40];
    __shared__ ushort_t Bl[64][40];
    f32x4 acc[2][2] = {};
    const int lrow = tid >> 2, lk = (tid & 3) * 8;
    for (int k0 = 0; k0 < H_; k0 += 32) {
        uint4 va = *(const uint4*)&hstates[(size_t)(mb*64 + lrow)*H_ + k0 + lk];
        *(uint4*)&Al[lrow][lk] = va;
        const float* ws = &Wfc[(size_t)(nb*64 + lrow)*H_ + k0 + lk];
        #pragma unroll
        for (int i = 0; i < 8; ++i) Bl[lrow][lk+i] = f2b(ws[i]);
        __syncthreads();
        const int fr = lane & 15, fk = (lane >> 4) * 8;
        #pragma unroll
        for (int mt = 0; mt < 2; ++mt) {
            bf16x8 a = *(const bf16x8*)&Al[wm*32 + mt*16 + fr][fk];
            #pragma unroll
            for (int nt = 0; nt < 2; ++nt) {
                bf16x8 b = *(const bf16x8*)&Bl[wn*32 + nt*16 + fr][fk];
                acc[mt][nt] = __builtin_amdgcn_mfma_f32_16x16x32_bf16(a, b, acc[mt][nt], 0, 0, 0);
            }
        }
        __syncthreads();
    }
    const int fr = lane & 15, fm = (lane >> 4) * 4;
    #pragma unroll
    for (int mt = 0; mt < 2; ++mt)
    #pragma unroll
    for (int nt = 0; nt < 2; ++nt)
    #pragma unroll
    for (int i = 0; i < 4; ++i) {
        int R  = mb*64 + wm*32 + mt*16 + fm + i;     // b*T + t
        int gn = nb*64 + wn*32 + nt*16 + fr;
        int b  = R >> 10, t = R & (T_ - 1);
        float mval = sm[b*S_ + (t >> 2)];
        out[(size_t)R*O_ + gn] = (acc[mt][nt][i] + bfc[gn]) * mval;
    }
}

// ---------------------------------------------------------------------------
// y_res (as f32) and ok (as f32 0/1)
// ---------------------------------------------------------------------------
__global__ void tail_kernel(const int* __restrict__ y, const float* __restrict__ sm,
                            float* __restrict__ yout, float* __restrict__ okout) {
    int i = blockIdx.x * 256 + threadIdx.x;
    if (i < B_ * T_) {
        int b = i >> 10, t = i & 1023, s = t >> 2;
        yout[i]  = (float)y[b*S_ + s];
        okout[i] = (sm[b*S_ + s] != 0.0f) ? 1.0f : 0.0f;
    }
}

// ---------------------------------------------------------------------------
extern "C" void kernel_launch(void* const* d_in, const int* in_sizes, int n_in,
                              void* d_out, int out_size, void* d_ws, size_t ws_size,
                              hipStream_t stream) {
    (void)in_sizes; (void)n_in; (void)out_size; (void)ws_size;
    const float* x   = (const float*)d_in[0];
    const int*   y   = (const int*)d_in[1];
    const float* sm  = (const float*)d_in[2];
    const float* Wih = (const float*)d_in[4];
    const float* Whh = (const float*)d_in[5];
    const float* bih = (const float*)d_in[6];
    const float* bhh = (const float*)d_in[7];
    const float* Wfc = (const float*)d_in[8];
    const float* bfc = (const float*)d_in[9];

    char* ws = (char*)d_ws;
    ushort_t* gi      = (ushort_t*)ws;                                  // 100,663,296 B
    ushort_t* hstates = (ushort_t*)(ws + 100663296);                    // 134,217,728 B
    ushort_t* xbuf    = (ushort_t*)(ws + 100663296 + 134217728);        //     262,144 B
    int*      flags   = (int*)(ws + 100663296 + 134217728 + 262144);    //       4 KB

    hipMemsetAsync(flags, 0, 4096, stream);

    hipLaunchKernelGGL(gi_gemm, dim3((B_*S_/64)*(H3_/64)), dim3(256), 0, stream,
                       x, Wih, bih, gi);

    void* args[] = { (void*)&gi, (void*)&Whh, (void*)&bhh, (void*)&hstates,
                     (void*)&xbuf, (void*)&flags };
    hipLaunchCooperativeKernel((void*)rec_kernel, dim3(NC_*CPC_), dim3(256), args, 0, stream);

    hipLaunchKernelGGL(logits_gemm, dim3((B_*T_/64)*(O_/64)), dim3(256), 0, stream,
                       hstates, Wfc, bfc, sm, (float*)d_out);

    float* yout  = (float*)d_out + (size_t)B_*T_*O_;
    float* okout = yout + (size_t)B_*T_;
    hipLaunchKernelGGL(tail_kernel, dim3(B_*T_/256), dim3(256), 0, stream,
                       y, sm, yout, okout);
}

// Round 8
// 3655.198 us; speedup vs baseline: 2.3235x; 1.6052x over previous
//
#include <hip/hip_runtime.h>
#include <hip/hip_bf16.h>

#define B_ 64
#define S_ 256
#define IN_ 512
#define H_ 1024
#define O_ 512
#define K_ 4
#define T_ (S_*K_)      // 1024
#define H3_ (3*H_)      // 3072

#define NC_ 8           // clusters
#define CPC_ 32         // WGs per cluster
#define RPC_ 8          // batch rows per cluster

typedef __attribute__((ext_vector_type(8))) short bf16x8;
typedef __attribute__((ext_vector_type(4))) float f32x4;
typedef __attribute__((ext_vector_type(4))) unsigned int uint32x4;
typedef unsigned short ushort_t;
typedef unsigned int uint_t;
typedef unsigned long long ull_t;

__device__ __forceinline__ ushort_t f2b(float f) {
    union { float f; unsigned u; } v; v.f = f;
    unsigned r = v.u + 0x7FFFu + ((v.u >> 16) & 1u);
    return (ushort_t)(r >> 16);
}
__device__ __forceinline__ float b2f(ushort_t h) {
    union { unsigned u; float f; } v; v.u = ((unsigned)h) << 16; return v.f;
}

// ---------------------------------------------------------------------------
// gi = x @ W_ih^T + b_ih   (bf16 output), M=16384, N=3072, K=512
// ---------------------------------------------------------------------------
__global__ __launch_bounds__(256) void gi_gemm(const float* __restrict__ x,
                                               const float* __restrict__ Wih,
                                               const float* __restrict__ bih,
                                               ushort_t* __restrict__ gi) {
    const int NB = H3_ / 64;                 // 48
    const int nb = blockIdx.x % NB;
    const int mb = blockIdx.x / NB;
    const int tid = threadIdx.x, lane = tid & 63, w = tid >> 6;
    const int wm = w >> 1, wn = w & 1;
    __shared__ ushort_t Al[64][40];
    __shared__ ushort_t Bl[64][40];
    f32x4 acc[2][2] = {};
    const int lrow = tid >> 2, lk = (tid & 3) * 8;
    for (int k0 = 0; k0 < IN_; k0 += 32) {
        const float* xs = &x[(size_t)(mb*64 + lrow)*IN_ + k0 + lk];
        const float* ws = &Wih[(size_t)(nb*64 + lrow)*IN_ + k0 + lk];
        #pragma unroll
        for (int i = 0; i < 8; ++i) Al[lrow][lk+i] = f2b(xs[i]);
        #pragma unroll
        for (int i = 0; i < 8; ++i) Bl[lrow][lk+i] = f2b(ws[i]);
        __syncthreads();
        const int fr = lane & 15, fk = (lane >> 4) * 8;
        #pragma unroll
        for (int mt = 0; mt < 2; ++mt) {
            bf16x8 a = *(const bf16x8*)&Al[wm*32 + mt*16 + fr][fk];
            #pragma unroll
            for (int nt = 0; nt < 2; ++nt) {
                bf16x8 b = *(const bf16x8*)&Bl[wn*32 + nt*16 + fr][fk];
                acc[mt][nt] = __builtin_amdgcn_mfma_f32_16x16x32_bf16(a, b, acc[mt][nt], 0, 0, 0);
            }
        }
        __syncthreads();
    }
    const int fr = lane & 15, fm = (lane >> 4) * 4;
    #pragma unroll
    for (int mt = 0; mt < 2; ++mt)
    #pragma unroll
    for (int nt = 0; nt < 2; ++nt)
    #pragma unroll
    for (int i = 0; i < 4; ++i) {
        int gm = mb*64 + wm*32 + mt*16 + fm + i;
        int gn = nb*64 + wn*32 + nt*16 + fr;
        gi[(size_t)gm*H3_ + gn] = f2b(acc[mt][nt][i] + bih[gn]);
    }
}

// ---------------------------------------------------------------------------
// Persistent recurrent kernel. 256 WGs = 8 clusters x 32 WGs (c = bid&7,
// cu = bid>>3 -- deterministic; NO dispatch-locality assumption). All
// h-exchange + flags use R5-proven agent-scope semantics. Each WG owns 32
// h-cols: r-gate (32 rows) + z-gate lower half (16 rows) in LDS (99KB),
// z upper half + n-gate (48 rows total) in ~96 VGPRs.
// ---------------------------------------------------------------------------
__global__ __launch_bounds__(256) void rec_kernel(const ushort_t* __restrict__ gi,
                                                  const float* __restrict__ Whh,
                                                  const float* __restrict__ bhh,
                                                  ushort_t* __restrict__ hstates,
                                                  ushort_t* __restrict__ xbuf,
                                                  int* __restrict__ flags) {
    const int bid = blockIdx.x;
    const int c  = bid & 7;          // cluster
    const int cu = bid >> 3;         // slot within cluster, 0..31
    const int tid = threadIdx.x, lane = tid & 63, w = tid >> 6;
    const int r_el = tid >> 5, jl = tid & 31;   // elementwise mapping (8x32)
    const int fr = lane & 15, koff8 = (lane >> 4) << 3;
    const int colbase = cu << 5;     // 32 h-cols per WG
    const int b0 = c * RPC_;         // batch row base

    __shared__ ushort_t wlds[48][1032];   // 99072 B: rows 0..31 r-gate, 32..47 z-gate lo
    __shared__ float red[4][8][100];      // 12800 B  per-wave partials

    // ---- stage LDS-resident weight rows (once)
    for (int e = tid * 4; e < 48 * 1024; e += 256 * 4) {
        int rr = e >> 10, k = e & 1023;
        int wrow = (rr < 32) ? (colbase + rr) : (H_ + colbase + (rr - 32));
        const float* src = &Whh[(size_t)wrow*H_ + k];
        #pragma unroll
        for (int i = 0; i < 4; ++i) wlds[rr][k + i] = f2b(src[i]);
    }
    // ---- register-resident weight fragments (once): z hi, n lo, n hi
    bf16x8 bz1[8], bn0[8], bn1[8];
    #pragma unroll
    for (int ks = 0; ks < 8; ++ks) {
        const int kk = (w << 8) + (ks << 5) + koff8;
        const float* sz = &Whh[(size_t)(H_   + colbase + 16 + fr)*H_ + kk];
        const float* s0 = &Whh[(size_t)(2*H_ + colbase      + fr)*H_ + kk];
        const float* s1 = &Whh[(size_t)(2*H_ + colbase + 16 + fr)*H_ + kk];
        bf16x8 tz, t0, t1;
        #pragma unroll
        for (int i = 0; i < 8; ++i) {
            tz[i] = (short)f2b(sz[i]); t0[i] = (short)f2b(s0[i]); t1[i] = (short)f2b(s1[i]);
        }
        bz1[ks] = tz; bn0[ks] = t0; bn1[ks] = t1;
    }
    const float bh_r = bhh[colbase + jl];
    const float bh_z = bhh[H_ + colbase + jl];
    const float bh_n = bhh[2*H_ + colbase + jl];

    // gi double-buffer
    ushort_t g_r, g_z, g_n, p_r = 0, p_z = 0, p_n = 0;
    {
        size_t row = ((size_t)(b0 + r_el)*S_ + 0)*H3_ + colbase + jl;
        g_r = gi[row]; g_z = gi[row + H_]; g_n = gi[row + 2*H_];
    }
    float gir = 0.f, giz = 0.f, gin = 0.f;

    // per-lane constant part of the A-fragment byte address.
    // Cluster region: 2 slots x 16 rows x 2KB = 64KB. Rows 8..15 are pads,
    // never written; any finite garbage there only feeds discarded C rows.
    const char* xb_lane = (const char*)xbuf
        + ((size_t)c << 16)                 // cluster region (64 KB)
        + (size_t)fr * 2048                 // row (1024 bf16)
        + (w << 9)                          // wave's K-quarter
        + ((lane >> 4) << 4);               // 16B sub-chunk

    float h_prev = 0.f;
    int* cflags = &flags[c << 5];           // 32 ints per cluster
    __syncthreads();                        // wlds ready

    for (int t = 0; t < T_; ++t) {
        // ---- tick top: gi consume + prefetch
        if ((t & 3) == 0) {
            if (t > 0) { g_r = p_r; g_z = p_z; g_n = p_n; }
            gir = b2f(g_r); giz = b2f(g_z); gin = b2f(g_n);
            int sn = (t >> 2) + 1; if (sn > S_ - 1) sn = S_ - 1;
            size_t row = ((size_t)(b0 + r_el)*S_ + sn)*H3_ + colbase + jl;
            p_r = gi[row]; p_z = gi[row + H_]; p_n = gi[row + 2*H_];
        }

        // ---- A-fragments: 8 pipelined device-scope loads + one vmcnt(0)
        uint32x4 f0 = {}, f1 = {}, f2 = {}, f3 = {}, f4 = {}, f5 = {}, f6 = {}, f7 = {};
        if (t > 0) {
            const char* ab = xb_lane + (((size_t)((t - 1) & 1)) << 15);
            asm volatile(
                "global_load_dwordx4 %0, %8, off sc0 sc1\n\t"
                "global_load_dwordx4 %1, %8, off offset:64 sc0 sc1\n\t"
                "global_load_dwordx4 %2, %8, off offset:128 sc0 sc1\n\t"
                "global_load_dwordx4 %3, %8, off offset:192 sc0 sc1\n\t"
                "global_load_dwordx4 %4, %8, off offset:256 sc0 sc1\n\t"
                "global_load_dwordx4 %5, %8, off offset:320 sc0 sc1\n\t"
                "global_load_dwordx4 %6, %8, off offset:384 sc0 sc1\n\t"
                "global_load_dwordx4 %7, %8, off offset:448 sc0 sc1\n\t"
                "s_waitcnt vmcnt(0)"
                : "=&v"(f0), "=&v"(f1), "=&v"(f2), "=&v"(f3),
                  "=&v"(f4), "=&v"(f5), "=&v"(f6), "=&v"(f7)
                : "v"(ab)
                : "memory");
            __builtin_amdgcn_sched_barrier(0);
        }
        bf16x8 afr[8];
        afr[0] = *(bf16x8*)&f0; afr[1] = *(bf16x8*)&f1;
        afr[2] = *(bf16x8*)&f2; afr[3] = *(bf16x8*)&f3;
        afr[4] = *(bf16x8*)&f4; afr[5] = *(bf16x8*)&f5;
        afr[6] = *(bf16x8*)&f6; afr[7] = *(bf16x8*)&f7;

        // ---- MFMA: 6 output tiles (r0,r1,z0,z1,n0,n1) x 8 K-steps
        f32x4 ar0 = {}, ar1 = {}, az0 = {}, az1 = {}, an0 = {}, an1 = {};
        #pragma unroll
        for (int ks = 0; ks < 8; ++ks) {
            const int k = (w << 8) + (ks << 5) + koff8;
            bf16x8 br0 = *(const bf16x8*)&wlds[fr][k];
            bf16x8 br1 = *(const bf16x8*)&wlds[16 + fr][k];
            bf16x8 bz0 = *(const bf16x8*)&wlds[32 + fr][k];
            ar0 = __builtin_amdgcn_mfma_f32_16x16x32_bf16(afr[ks], br0, ar0, 0, 0, 0);
            ar1 = __builtin_amdgcn_mfma_f32_16x16x32_bf16(afr[ks], br1, ar1, 0, 0, 0);
            az0 = __builtin_amdgcn_mfma_f32_16x16x32_bf16(afr[ks], bz0, az0, 0, 0, 0);
            az1 = __builtin_amdgcn_mfma_f32_16x16x32_bf16(afr[ks], bz1[ks], az1, 0, 0, 0);
            an0 = __builtin_amdgcn_mfma_f32_16x16x32_bf16(afr[ks], bn0[ks], an0, 0, 0, 0);
            an1 = __builtin_amdgcn_mfma_f32_16x16x32_bf16(afr[ks], bn1[ks], an1, 0, 0, 0);
        }
        if (lane < 32) {                      // C rows 0..7 live in lanes 0..31
            const int m = (lane >> 4) << 2, n = fr;
            #pragma unroll
            for (int i = 0; i < 4; ++i) {
                red[w][m+i][n]      = ar0[i];
                red[w][m+i][16+n]   = ar1[i];
                red[w][m+i][32+n]   = az0[i];
                red[w][m+i][48+n]   = az1[i];
                red[w][m+i][64+n]   = an0[i];
                red[w][m+i][80+n]   = an1[i];
            }
        }
        __syncthreads();

        // ---- elementwise GRU update: thread (r_el, jl), 8x32
        float ghr = red[0][r_el][jl]    + red[1][r_el][jl]    + red[2][r_el][jl]    + red[3][r_el][jl];
        float ghz = red[0][r_el][32+jl] + red[1][r_el][32+jl] + red[2][r_el][32+jl] + red[3][r_el][32+jl];
        float ghn = red[0][r_el][64+jl] + red[1][r_el][64+jl] + red[2][r_el][64+jl] + red[3][r_el][64+jl];
        float rr_ = 1.f / (1.f + __expf(-(gir + ghr + bh_r)));
        float zz  = 1.f / (1.f + __expf(-(giz + ghz + bh_z)));
        float nn  = tanhf(gin + rr_ * (ghn + bh_n));
        float hn  = (1.f - zz) * nn + zz * h_prev;
        h_prev = hn;
        ushort_t hb = f2b(hn);

        // trajectory (read by logits_gemm after kernel end): plain store
        hstates[((size_t)(b0 + r_el)*T_ + t)*H_ + colbase + jl] = hb;
        // exchange: agent-scope store into ping-pong slot t&1
        size_t xidx = ((size_t)c << 15) + ((size_t)(t & 1) << 14) + (r_el << 10) + colbase + jl;
        __hip_atomic_store(&xbuf[xidx], hb, __ATOMIC_RELAXED, __HIP_MEMORY_SCOPE_AGENT);

        // barrier drains vmcnt(0) -> stores acked before flag issues
        __syncthreads();

        if (w == 0) {
            if (lane == 0)
                __hip_atomic_store(&cflags[cu], t + 1, __ATOMIC_RELAXED,
                                   __HIP_MEMORY_SCOPE_AGENT);
            for (;;) {
                int v = t + 1;
                if (lane < 32)
                    v = __hip_atomic_load(&cflags[lane], __ATOMIC_RELAXED,
                                          __HIP_MEMORY_SCOPE_AGENT);
                if (__all(v >= t + 1)) break;
                __builtin_amdgcn_s_sleep(1);
            }
        }
        __syncthreads();
    }
}

// ---------------------------------------------------------------------------
// logits = (hstates @ W_fc^T + b_fc) * seq_mask  (f32 out, straight to d_out)
// ---------------------------------------------------------------------------
__global__ __launch_bounds__(256) void logits_gemm(const ushort_t* __restrict__ hstates,
                                                   const float* __restrict__ Wfc,
                                                   const float* __restrict__ bfc,
                                                   const float* __restrict__ sm,
                                                   float* __restrict__ out) {
    const int NB = O_ / 64;                  // 8
    const int nb = blockIdx.x % NB;
    const int mb = blockIdx.x / NB;
    const int tid = threadIdx.x, lane = tid & 63, w = tid >> 6;
    const int wm = w >> 1, wn = w & 1;
    __shared__ ushort_t Al[64][40];
    __shared__ ushort_t Bl[64][40];
    f32x4 acc[2][2] = {};
    const int lrow = tid >> 2, lk = (tid & 3) * 8;
    for (int k0 = 0; k0 < H_; k0 += 32) {
        uint4 va = *(const uint4*)&hstates[(size_t)(mb*64 + lrow)*H_ + k0 + lk];
        *(uint4*)&Al[lrow][lk] = va;
        const float* ws = &Wfc[(size_t)(nb*64 + lrow)*H_ + k0 + lk];
        #pragma unroll
        for (int i = 0; i < 8; ++i) Bl[lrow][lk+i] = f2b(ws[i]);
        __syncthreads();
        const int fr = lane & 15, fk = (lane >> 4) * 8;
        #pragma unroll
        for (int mt = 0; mt < 2; ++mt) {
            bf16x8 a = *(const bf16x8*)&Al[wm*32 + mt*16 + fr][fk];
            #pragma unroll
            for (int nt = 0; nt < 2; ++nt) {
                bf16x8 b = *(const bf16x8*)&Bl[wn*32 + nt*16 + fr][fk];
                acc[mt][nt] = __builtin_amdgcn_mfma_f32_16x16x32_bf16(a, b, acc[mt][nt], 0, 0, 0);
            }
        }
        __syncthreads();
    }
    const int fr = lane & 15, fm = (lane >> 4) * 4;
    #pragma unroll
    for (int mt = 0; mt < 2; ++mt)
    #pragma unroll
    for (int nt = 0; nt < 2; ++nt)
    #pragma unroll
    for (int i = 0; i < 4; ++i) {
        int R  = mb*64 + wm*32 + mt*16 + fm + i;     // b*T + t
        int gn = nb*64 + wn*32 + nt*16 + fr;
        int b  = R >> 10, t = R & (T_ - 1);
        float mval = sm[b*S_ + (t >> 2)];
        out[(size_t)R*O_ + gn] = (acc[mt][nt][i] + bfc[gn]) * mval;
    }
}

// ---------------------------------------------------------------------------
__global__ void tail_kernel(const int* __restrict__ y, const float* __restrict__ sm,
                            float* __restrict__ yout, float* __restrict__ okout) {
    int i = blockIdx.x * 256 + threadIdx.x;
    if (i < B_ * T_) {
        int b = i >> 10, t = i & 1023, s = t >> 2;
        yout[i]  = (float)y[b*S_ + s];
        okout[i] = (sm[b*S_ + s] != 0.0f) ? 1.0f : 0.0f;
    }
}

// ---------------------------------------------------------------------------
extern "C" void kernel_launch(void* const* d_in, const int* in_sizes, int n_in,
                              void* d_out, int out_size, void* d_ws, size_t ws_size,
                              hipStream_t stream) {
    (void)in_sizes; (void)n_in; (void)out_size; (void)ws_size;
    const float* x   = (const float*)d_in[0];
    const int*   y   = (const int*)d_in[1];
    const float* sm  = (const float*)d_in[2];
    const float* Wih = (const float*)d_in[4];
    const float* Whh = (const float*)d_in[5];
    const float* bih = (const float*)d_in[6];
    const float* bhh = (const float*)d_in[7];
    const float* Wfc = (const float*)d_in[8];
    const float* bfc = (const float*)d_in[9];

    char* ws = (char*)d_ws;
    ushort_t* gi      = (ushort_t*)ws;                                  // 100,663,296 B
    ushort_t* hstates = (ushort_t*)(ws + 100663296);                    // 134,217,728 B
    ushort_t* xbuf    = (ushort_t*)(ws + 100663296 + 134217728);        //     524,288 B
    int*      flags   = (int*)(ws + 100663296 + 134217728 + 524288);    //       4 KB

    hipMemsetAsync(flags, 0, 4096, stream);

    hipLaunchKernelGGL(gi_gemm, dim3((B_*S_/64)*(H3_/64)), dim3(256), 0, stream,
                       x, Wih, bih, gi);

    void* args[] = { (void*)&gi, (void*)&Whh, (void*)&bhh, (void*)&hstates,
                     (void*)&xbuf, (void*)&flags };
    hipLaunchCooperativeKernel((void*)rec_kernel, dim3(NC_*CPC_), dim3(256), args, 0, stream);

    hipLaunchKernelGGL(logits_gemm, dim3((B_*T_/64)*(O_/64)), dim3(256), 0, stream,
                       hstates, Wfc, bfc, sm, (float*)d_out);

    float* yout  = (float*)d_out + (size_t)B_*T_*O_;
    float* okout = yout + (size_t)B_*T_;
    hipLaunchKernelGGL(tail_kernel, dim3(B_*T_/256), dim3(256), 0, stream,
                       y, sm, yout, okout);
}